// Round 5
// baseline (1176.849 us; speedup 1.0000x reference)
//
#include <hip/hip_runtime.h>
#include <math.h>

#define N_NODES 20000
#define N_EDGES 320000
#define MUL 64
#define NUM_BASIS 8
#define HID 64
#define NSPEC 4

#define LIN_NORM     0.125f          // 1/sqrt(64)
#define INV_SQRT8    0.3535533906f   // 1/sqrt(8)
#define LIN2_NORM    0.08838834765f  // 1/sqrt(128)
#define SC_NORM      0.0625f         // 1/sqrt(64*4)
#define INV_NEIGH    0.0625f         // 1/16
#define INV_SQRT3    0.5773502692f
#define SILU_NORM    1.679177f

typedef float v2f __attribute__((ext_vector_type(2)));

__device__ __forceinline__ v2f mkv2(float a, float b) { v2f r; r.x = a; r.y = b; return r; }

__device__ __forceinline__ float silu_n(float x) {
    float s = 1.0f / (1.0f + __expf(-x));
    return x * s * SILU_NORM;
}

// ---------------------------------------------------------------------------
// CSR build: histogram -> 1-block scan -> scatter (permutation sorted by dst)
// ---------------------------------------------------------------------------
__global__ __launch_bounds__(256) void k_hist(const int* __restrict__ edst,
                                              int* __restrict__ counts)
{
    int e = blockIdx.x * blockDim.x + threadIdx.x;
    if (e < N_EDGES) atomicAdd(&counts[edst[e]], 1);
}

#define SCAN_T 1024
__global__ __launch_bounds__(SCAN_T) void k_scan(const int* __restrict__ counts,
                                                 int* __restrict__ cursor)
{
    __shared__ int part[SCAN_T];
    int t = threadIdx.x;
    const int CH = (N_NODES + SCAN_T - 1) / SCAN_T;   // 20
    int b0 = t * CH;
    int s = 0;
    for (int i = 0; i < CH; ++i) {
        int idx = b0 + i;
        if (idx < N_NODES) s += counts[idx];
    }
    part[t] = s;
    __syncthreads();
    for (int off = 1; off < SCAN_T; off <<= 1) {
        int v = (t >= off) ? part[t - off] : 0;
        __syncthreads();
        part[t] += v;
        __syncthreads();
    }
    int run = (t == 0) ? 0 : part[t - 1];
    for (int i = 0; i < CH; ++i) {
        int idx = b0 + i;
        if (idx < N_NODES) {
            cursor[idx] = run;
            run += counts[idx];
        }
    }
}

__global__ __launch_bounds__(256) void k_fill(const int* __restrict__ edst,
                                              int* __restrict__ cursor,
                                              int* __restrict__ elist,
                                              int* __restrict__ dlist)
{
    int e = blockIdx.x * blockDim.x + threadIdx.x;
    if (e < N_EDGES) {
        int d = edst[e];
        int pos = atomicAdd(&cursor[d], 1);
        elist[pos] = e;
        dlist[pos] = d;
    }
}

// ---------------------------------------------------------------------------
// Kernel A: per-node lin1. Activations via wave-uniform scalar loads;
// weights lane-coalesced. v stored planar: v[p][n][u]
// ---------------------------------------------------------------------------
__global__ __launch_bounds__(256) void k_node_lin1(
    const float* __restrict__ ns, const float* __restrict__ nv,
    const float* __restrict__ Ws, const float* __restrict__ Wv,
    float* __restrict__ s_out, float* __restrict__ v_out)
{
    int lane = threadIdx.x & 63;
    int gwave = (blockIdx.x * blockDim.x + threadIdx.x) >> 6;
    int n = __builtin_amdgcn_readfirstlane(gwave);
    if (n >= N_NODES) return;
    const float* nsp = ns + (size_t)n * 64;
    const float* nvp = nv + (size_t)n * 192;
    float as = 0.f, a0 = 0.f, a1 = 0.f, a2 = 0.f;
    #pragma unroll 8
    for (int u = 0; u < 64; ++u) {
        float ws = Ws[u * 64 + lane];
        float wv = Wv[u * 64 + lane];
        as += nsp[u] * ws;
        a0 += nvp[u * 3 + 0] * wv;
        a1 += nvp[u * 3 + 1] * wv;
        a2 += nvp[u * 3 + 2] * wv;
    }
    s_out[(size_t)n * 64 + lane] = as * LIN_NORM;
    v_out[0 * (size_t)N_NODES * 64 + (size_t)n * 64 + lane] = a0 * LIN_NORM;
    v_out[1 * (size_t)N_NODES * 64 + (size_t)n * 64 + lane] = a1 * LIN_NORM;
    v_out[2 * (size_t)N_NODES * 64 + (size_t)n * 64 + lane] = a2 * LIN_NORM;
}

// ---------------------------------------------------------------------------
// Kernel B0: fc0 over sorted edges. lane=hidden channel. emb via s_load.
// Writes h0[pos][64] in sorted position order (coalesced, streamed).
// ---------------------------------------------------------------------------
#define EB0 8
__global__ __launch_bounds__(256) void k_fc0(
    const float* __restrict__ emb, const int* __restrict__ elist,
    const float* __restrict__ W0, float* __restrict__ h0)
{
    int lane = threadIdx.x & 63;
    int gwave = (blockIdx.x * blockDim.x + threadIdx.x) >> 6;
    int base = __builtin_amdgcn_readfirstlane(gwave * EB0);
    if (base >= N_EDGES) return;
    float w0r[8];
    #pragma unroll
    for (int k = 0; k < 8; ++k) w0r[k] = W0[k * 64 + lane];
    #pragma unroll
    for (int e = 0; e < EB0; ++e) {
        int eid = __builtin_amdgcn_readfirstlane(elist[base + e]);
        const float* ep = emb + (size_t)eid * 8;        // uniform -> s_load
        float a = 0.f;
        #pragma unroll
        for (int k = 0; k < 8; ++k) a += ep[k] * w0r[k];
        h0[(size_t)(base + e) * 64 + lane] = silu_n(a * INV_SQRT8);
    }
}

// ---------------------------------------------------------------------------
// Kernel B1: fc1. h1[pos] = silu(h0[pos] @ W1 / 8). Activations via s_load
// (SGPR, no cross-lane), weights lane-coalesced, float2-packed FMA.
// ---------------------------------------------------------------------------
#define EB1 8
__global__ __launch_bounds__(256) void k_fc1(
    const float* __restrict__ h0, const float* __restrict__ W1,
    float* __restrict__ h1)
{
    int lane = threadIdx.x & 63;
    int gwave = (blockIdx.x * blockDim.x + threadIdx.x) >> 6;
    int base = __builtin_amdgcn_readfirstlane(gwave * EB1);
    if (base >= N_EDGES) return;
    const float* hp = h0 + (size_t)base * 64;           // uniform base
    v2f acc2[EB1];
    #pragma unroll
    for (int e = 0; e < EB1; ++e) acc2[e] = mkv2(0.f, 0.f);
    #pragma unroll 8
    for (int k = 0; k < 64; k += 2) {
        v2f wv = mkv2(W1[k * 64 + lane], W1[(k + 1) * 64 + lane]);
        #pragma unroll
        for (int e = 0; e < EB1; ++e) {
            v2f h2 = mkv2(hp[e * 64 + k], hp[e * 64 + k + 1]);  // s_load x2
            acc2[e] += wv * h2;
        }
    }
    #pragma unroll
    for (int e = 0; e < EB1; ++e) {
        float a = (acc2[e].x + acc2[e].y) * 0.125f;
        h1[(size_t)(base + e) * 64 + lane] = silu_n(a);
    }
}

// ---------------------------------------------------------------------------
// Kernel B2: fc2 + tensor product + run-merged scatter over sorted edges.
// lane = channel u. h1 rows via wave-uniform s_load; W2 in VGPRs per k-chunk.
// ---------------------------------------------------------------------------
#define EB2 8
__global__ __launch_bounds__(256) void k_tp(
    const float* __restrict__ h1, const float* __restrict__ sh,
    const int* __restrict__ esrc,
    const int* __restrict__ elist, const int* __restrict__ dlist,
    const float* __restrict__ W2,
    const float* __restrict__ s_in, const float* __restrict__ v_in,
    float* __restrict__ s_agg, float* __restrict__ v_agg)
{
    const size_t NP2 = (size_t)N_NODES * 128;
    const size_t NV  = (size_t)N_NODES * 64;
    int lane = threadIdx.x & 63;
    int gwave = (blockIdx.x * blockDim.x + threadIdx.x) >> 6;
    int base = __builtin_amdgcn_readfirstlane(gwave * EB2);
    if (base >= N_EDGES) return;

    int eids[EB2], dsts[EB2], srcs[EB2];
    #pragma unroll
    for (int e = 0; e < EB2; ++e) {
        eids[e] = __builtin_amdgcn_readfirstlane(elist[base + e]);
        dsts[e] = __builtin_amdgcn_readfirstlane(dlist[base + e]);
        srcs[e] = __builtin_amdgcn_readfirstlane(esrc[eids[e]]);
    }

    // fc2: w[e][g*64+lane] = sum_k h1[e][k] * W2[k][g*64+lane]
    float aw[EB2][4];
    #pragma unroll
    for (int e = 0; e < EB2; ++e)
        #pragma unroll
        for (int g = 0; g < 4; ++g) aw[e][g] = 0.f;

    #pragma unroll
    for (int c = 0; c < 4; ++c) {                 // k-chunks of 16
        v2f wpk[8][4];
        #pragma unroll
        for (int p = 0; p < 8; ++p) {
            int k = c * 16 + p * 2;
            #pragma unroll
            for (int g = 0; g < 4; ++g)
                wpk[p][g] = mkv2(W2[(size_t)k * 256 + g * 64 + lane],
                                 W2[(size_t)(k + 1) * 256 + g * 64 + lane]);
        }
        #pragma unroll
        for (int e = 0; e < EB2; ++e) {
            const float* hp = h1 + (size_t)(base + e) * 64 + c * 16;  // uniform
            v2f t0 = mkv2(0.f, 0.f), t1 = mkv2(0.f, 0.f);
            v2f t2 = mkv2(0.f, 0.f), t3 = mkv2(0.f, 0.f);
            #pragma unroll
            for (int p = 0; p < 8; ++p) {
                v2f h2 = mkv2(hp[2 * p], hp[2 * p + 1]);   // s_load
                t0 += wpk[p][0] * h2;
                t1 += wpk[p][1] * h2;
                t2 += wpk[p][2] * h2;
                t3 += wpk[p][3] * h2;
            }
            aw[e][0] += t0.x + t0.y;
            aw[e][1] += t1.x + t1.y;
            aw[e][2] += t2.x + t2.y;
            aw[e][3] += t3.x + t3.y;
        }
    }

    // tensor product + run-merged scatter (HW fp32 atomics)
    float accA = 0.f, accD = 0.f;
    float aB0 = 0.f, aB1 = 0.f, aB2 = 0.f;
    float aC0 = 0.f, aC1 = 0.f, aC2 = 0.f;

    auto flush = [&](int d) {
        size_t db = (size_t)d * 128;
        unsafeAtomicAdd(&s_agg[db + lane],              accA);
        unsafeAtomicAdd(&s_agg[db + 64 + lane],         accD);
        unsafeAtomicAdd(&v_agg[0 * NP2 + db + lane],      aB0);
        unsafeAtomicAdd(&v_agg[1 * NP2 + db + lane],      aB1);
        unsafeAtomicAdd(&v_agg[2 * NP2 + db + lane],      aB2);
        unsafeAtomicAdd(&v_agg[0 * NP2 + db + 64 + lane], aC0);
        unsafeAtomicAdd(&v_agg[1 * NP2 + db + 64 + lane], aC1);
        unsafeAtomicAdd(&v_agg[2 * NP2 + db + 64 + lane], aC2);
        accA = accD = aB0 = aB1 = aB2 = aC0 = aC1 = aC2 = 0.f;
    };

    const float WSCALE = 0.125f * INV_NEIGH;
    int cur = dsts[0];
    const float4* sh4 = (const float4*)sh;
    #pragma unroll
    for (int e = 0; e < EB2; ++e) {
        if (dsts[e] != cur) { flush(cur); cur = dsts[e]; }
        int eid = eids[e];
        int src = srcs[e];
        float4 y = sh4[eid];                    // uniform -> s_load
        float se = s_in[(size_t)src * 64 + lane];
        float v0 = v_in[0 * NV + (size_t)src * 64 + lane];
        float v1 = v_in[1 * NV + (size_t)src * 64 + lane];
        float v2 = v_in[2 * NV + (size_t)src * 64 + lane];
        float wA = aw[e][0] * WSCALE;
        float wB = aw[e][1] * WSCALE;
        float wC = aw[e][2] * WSCALE;
        float wD = aw[e][3] * WSCALE;

        accA += wA * se * y.x;
        float dot = v0 * y.y + v1 * y.z + v2 * y.w;
        accD += wD * dot * INV_SQRT3;
        float bB = wB * se;
        aB0 += bB * y.y;
        aB1 += bB * y.z;
        aB2 += bB * y.w;
        float bC = wC * y.x;
        aC0 += bC * v0;
        aC1 += bC * v1;
        aC2 += bC * v2;
    }
    flush(cur);
}

// ---------------------------------------------------------------------------
// Kernel C: per-node epilogue. Activations via wave-uniform s_load (SGPR),
// weights lane-coalesced, float2-packed (sA,sB). No cross-lane ops.
// ---------------------------------------------------------------------------
#define NB 4
__global__ __launch_bounds__(256) void k_node_out(
    const float* __restrict__ ns, const float* __restrict__ nv,
    const float* __restrict__ na,
    const float* __restrict__ Wl2s, const float* __restrict__ Wl2v,
    const float* __restrict__ Wscs, const float* __restrict__ Wscv,
    const float* __restrict__ s_agg, const float* __restrict__ v_agg,
    float* __restrict__ out)
{
    const size_t NP2 = (size_t)N_NODES * 128;
    int lane = threadIdx.x & 63;
    int gwave = (blockIdx.x * blockDim.x + threadIdx.x) >> 6;
    int n0 = __builtin_amdgcn_readfirstlane(gwave * NB);
    if (n0 >= N_NODES) return;

    v2f sAB[NB];
    float vh[NB][3];
    #pragma unroll
    for (int j = 0; j < NB; ++j) {
        sAB[j] = mkv2(0.f, 0.f);
        vh[j][0] = 0.f; vh[j][1] = 0.f; vh[j][2] = 0.f;
    }

    // uniform activation base pointers
    const float* ap[NB]; const float* b0p[NB]; const float* b1p[NB]; const float* b2p[NB];
    const float* nsp[NB]; const float* nvp[NB];
    float pa[NB][4];
    #pragma unroll
    for (int j = 0; j < NB; ++j) {
        size_t nj = (size_t)(n0 + j);
        ap[j]  = s_agg + nj * 128;
        b0p[j] = v_agg + 0 * NP2 + nj * 128;
        b1p[j] = v_agg + 1 * NP2 + nj * 128;
        b2p[j] = v_agg + 2 * NP2 + nj * 128;
        nsp[j] = ns + nj * 64;
        nvp[j] = nv + nj * 192;
        #pragma unroll
        for (int q = 0; q < 4; ++q)
            pa[j][q] = na[nj * 4 + q] * SC_NORM;
    }

    // lin2 (s and v fused) over 128 aggregated channels
    #pragma unroll 4
    for (int u = 0; u < 128; ++u) {
        v2f w12 = mkv2(Wl2s[(size_t)u * 128 + lane], Wl2s[(size_t)u * 128 + 64 + lane]);
        float wv = Wl2v[(size_t)u * 64 + lane];
        #pragma unroll
        for (int j = 0; j < NB; ++j) {
            float a = ap[j][u];                           // s_load
            sAB[j] += w12 * mkv2(a, a);
            vh[j][0] += b0p[j][u] * wv;
            vh[j][1] += b1p[j][u] * wv;
            vh[j][2] += b2p[j][u] * wv;
        }
    }
    #pragma unroll
    for (int j = 0; j < NB; ++j) {
        sAB[j] *= mkv2(LIN2_NORM, LIN2_NORM);
        vh[j][0] *= LIN2_NORM; vh[j][1] *= LIN2_NORM; vh[j][2] *= LIN2_NORM;
    }

    // self-connection (fused)
    #pragma unroll 2
    for (int u = 0; u < 64; ++u) {
        #pragma unroll
        for (int q = 0; q < 4; ++q) {
            int idx = u * 4 + q;
            v2f wss = mkv2(Wscs[(size_t)idx * 128 + lane], Wscs[(size_t)idx * 128 + 64 + lane]);
            float wsv = Wscv[(size_t)idx * 64 + lane];
            #pragma unroll
            for (int j = 0; j < NB; ++j) {
                float su = nsp[j][u];                     // s_load
                float t = su * pa[j][q];
                sAB[j] += wss * mkv2(t, t);
                float tq = pa[j][q] * wsv;
                vh[j][0] += nvp[j][u * 3 + 0] * tq;
                vh[j][1] += nvp[j][u * 3 + 1] * tq;
                vh[j][2] += nvp[j][u * 3 + 2] * tq;
            }
        }
    }

    // epilogue + store
    #pragma unroll
    for (int j = 0; j < NB; ++j) {
        int n = n0 + j;
        float os = silu_n(sAB[j].x);
        float g  = silu_n(sAB[j].y);
        out[(size_t)n * 256 + lane] = os;
        out[(size_t)n * 256 + 64 + lane * 3 + 0] = g * vh[j][0];
        out[(size_t)n * 256 + 64 + lane * 3 + 1] = g * vh[j][1];
        out[(size_t)n * 256 + 64 + lane * 3 + 2] = g * vh[j][2];
    }
}

// ---------------------------------------------------------------------------
extern "C" void kernel_launch(void* const* d_in, const int* in_sizes, int n_in,
                              void* d_out, int out_size, void* d_ws, size_t ws_size,
                              hipStream_t stream)
{
    const float* node_scalars = (const float*)d_in[0];
    const float* node_vectors = (const float*)d_in[1];
    const float* node_attr    = (const float*)d_in[2];
    const float* edge_sh      = (const float*)d_in[3];
    const float* edge_emb     = (const float*)d_in[4];
    const int*   edge_src     = (const int*)d_in[5];
    const int*   edge_dst     = (const int*)d_in[6];
    const float* W_lin1_s = (const float*)d_in[7];
    const float* W_lin1_v = (const float*)d_in[8];
    const float* W_fc0    = (const float*)d_in[9];
    const float* W_fc1    = (const float*)d_in[10];
    const float* W_fc2    = (const float*)d_in[11];
    const float* W_lin2_s = (const float*)d_in[12];
    const float* W_lin2_v = (const float*)d_in[13];
    const float* W_sc_s   = (const float*)d_in[14];
    const float* W_sc_v   = (const float*)d_in[15];
    float* out = (float*)d_out;

    // workspace layout. h0 (E*64) aliases [s_agg|v_agg] (N*512 total) —
    // h0 is dead before the agg memset+k_tp, stream order guarantees safety.
    float* ws    = (float*)d_ws;
    float* h0    = ws;                                    // E*64 (alias region)
    float* s_agg = ws;                                    // N*128
    float* v_agg = s_agg + (size_t)N_NODES * 128;         // 3*N*128
    float* h1    = ws + (size_t)N_EDGES * 64;             // E*64
    float* s_buf = h1 + (size_t)N_EDGES * 64;             // N*64
    float* v_buf = s_buf + (size_t)N_NODES * 64;          // 3*N*64
    int*   counts = (int*)(v_buf + 3 * (size_t)N_NODES * 64);   // N
    int*   cursor = counts + N_NODES;                     // N
    int*   elist  = cursor + N_NODES;                     // E
    int*   dlist  = elist + N_EDGES;                      // E

    hipMemsetAsync(counts, 0, (size_t)N_NODES * sizeof(int), stream);

    // CSR build (dst-sorted permutation)
    {
        int blocks = (N_EDGES + 255) / 256;
        k_hist<<<blocks, 256, 0, stream>>>(edge_dst, counts);
        k_scan<<<1, SCAN_T, 0, stream>>>(counts, cursor);
        k_fill<<<blocks, 256, 0, stream>>>(edge_dst, cursor, elist, dlist);
    }
    // A: node lin1
    {
        int blocks = (N_NODES + 3) / 4;
        k_node_lin1<<<blocks, 256, 0, stream>>>(node_scalars, node_vectors,
                                                W_lin1_s, W_lin1_v, s_buf, v_buf);
    }
    // B0/B1: edge MLP stages (write h in sorted order; h0 aliases agg)
    {
        int blocks = (N_EDGES / EB0 + 3) / 4;   // 10000
        k_fc0<<<blocks, 256, 0, stream>>>(edge_emb, elist, W_fc0, h0);
        k_fc1<<<blocks, 256, 0, stream>>>(h0, W_fc1, h1);
    }
    // zero aggregation buffers (h0 is now dead)
    hipMemsetAsync(s_agg, 0, (size_t)N_NODES * 512 * sizeof(float), stream);
    // B2: fc2 + TP + scatter
    {
        int blocks = (N_EDGES / EB2 + 3) / 4;   // 10000
        k_tp<<<blocks, 256, 0, stream>>>(h1, edge_sh, edge_src, elist, dlist,
                                         W_fc2, s_buf, v_buf, s_agg, v_agg);
    }
    // C: node epilogue
    {
        int blocks = (N_NODES / NB + 3) / 4;    // 1250
        k_node_out<<<blocks, 256, 0, stream>>>(node_scalars, node_vectors, node_attr,
                                               W_lin2_s, W_lin2_v, W_sc_s, W_sc_v,
                                               s_agg, v_agg, out);
    }
}

// Round 6
// 584.449 us; speedup vs baseline: 2.0136x; 2.0136x over previous
//
#include <hip/hip_runtime.h>
#include <math.h>

#define N_NODES 20000
#define N_EDGES 320000
#define MUL 64
#define NUM_BASIS 8
#define HID 64
#define NSPEC 4

#define LIN_NORM     0.125f          // 1/sqrt(64)
#define INV_SQRT8    0.3535533906f   // 1/sqrt(8)
#define LIN2_NORM    0.08838834765f  // 1/sqrt(128)
#define SC_NORM      0.0625f         // 1/sqrt(64*4)
#define INV_NEIGH    0.0625f         // 1/16
#define INV_SQRT3    0.5773502692f
#define SILU_NORM    1.679177f

typedef __attribute__((ext_vector_type(8))) short bf16x8;
typedef __attribute__((ext_vector_type(4))) float f32x4;

__device__ __forceinline__ float silu_n(float x) {
    float s = 1.0f / (1.0f + __expf(-x));
    return x * s * SILU_NORM;
}

__device__ __forceinline__ float bcast(float x, int l) {
    return __uint_as_float(__builtin_amdgcn_readlane(__float_as_uint(x), l));
}
__device__ __forceinline__ int bcast_i(int x, int l) {
    return __builtin_amdgcn_readlane(x, l);
}

// fp32 -> bf16 with round-to-nearest-even
__device__ __forceinline__ unsigned short f2bf(float x) {
    unsigned int u = __float_as_uint(x);
    unsigned int r = (u + 0x7fffu + ((u >> 16) & 1u)) >> 16;
    return (unsigned short)r;
}

// ---------------------------------------------------------------------------
// CSR build: histogram -> 1-block scan -> scatter (permutation sorted by dst)
// ---------------------------------------------------------------------------
__global__ __launch_bounds__(256) void k_hist(const int* __restrict__ edst,
                                              int* __restrict__ counts)
{
    int e = blockIdx.x * blockDim.x + threadIdx.x;
    if (e < N_EDGES) atomicAdd(&counts[edst[e]], 1);
}

#define SCAN_T 1024
__global__ __launch_bounds__(SCAN_T) void k_scan(const int* __restrict__ counts,
                                                 int* __restrict__ cursor)
{
    __shared__ int part[SCAN_T];
    int t = threadIdx.x;
    const int CH = (N_NODES + SCAN_T - 1) / SCAN_T;   // 20
    int b0 = t * CH;
    int s = 0;
    for (int i = 0; i < CH; ++i) {
        int idx = b0 + i;
        if (idx < N_NODES) s += counts[idx];
    }
    part[t] = s;
    __syncthreads();
    for (int off = 1; off < SCAN_T; off <<= 1) {
        int v = (t >= off) ? part[t - off] : 0;
        __syncthreads();
        part[t] += v;
        __syncthreads();
    }
    int run = (t == 0) ? 0 : part[t - 1];
    for (int i = 0; i < CH; ++i) {
        int idx = b0 + i;
        if (idx < N_NODES) {
            cursor[idx] = run;
            run += counts[idx];
        }
    }
}

__global__ __launch_bounds__(256) void k_fill(const int* __restrict__ edst,
                                              int* __restrict__ cursor,
                                              int* __restrict__ elist,
                                              int* __restrict__ dlist)
{
    int e = blockIdx.x * blockDim.x + threadIdx.x;
    if (e < N_EDGES) {
        int d = edst[e];
        int pos = atomicAdd(&cursor[d], 1);
        elist[pos] = e;
        dlist[pos] = d;
    }
}

// ---------------------------------------------------------------------------
// Weight prep: swizzle W1 (64x64) and W2 (64x256) into bf16 B-fragment order
// for mfma_f32_16x16x32_bf16: frag(kt,nt), lane holds B[k=kt*32+q*8+j][n=nt*16+c]
// ---------------------------------------------------------------------------
__global__ __launch_bounds__(256) void k_wprep(
    const float* __restrict__ W1, const float* __restrict__ W2,
    unsigned short* __restrict__ w1f, unsigned short* __restrict__ w2f)
{
    int t = blockIdx.x * 256 + threadIdx.x;
    if (t < 512) {                       // W1: 8 frags (kt*4+nt)
        int f = t >> 6, lane = t & 63;
        int kt = f >> 2, nt = f & 3, q = lane >> 4, c = lane & 15;
        #pragma unroll
        for (int j = 0; j < 8; ++j) {
            int k = kt * 32 + q * 8 + j;
            int n = nt * 16 + c;
            w1f[(size_t)t * 8 + j] = f2bf(W1[k * 64 + n]);
        }
    } else if (t < 2560) {               // W2: 32 frags (kt*16+nt)
        int tt = t - 512;
        int f = tt >> 6, lane = tt & 63;
        int kt = f >> 4, nt = f & 15, q = lane >> 4, c = lane & 15;
        #pragma unroll
        for (int j = 0; j < 8; ++j) {
            int k = kt * 32 + q * 8 + j;
            int n = nt * 16 + c;
            w2f[(size_t)tt * 8 + j] = f2bf(W2[k * 256 + n]);
        }
    }
}

// ---------------------------------------------------------------------------
// Kernel A: per-node lin1 (unchanged from R4)
// ---------------------------------------------------------------------------
__global__ __launch_bounds__(256) void k_node_lin1(
    const float* __restrict__ ns, const float* __restrict__ nv,
    const float* __restrict__ Ws, const float* __restrict__ Wv,
    float* __restrict__ s_out, float* __restrict__ v_out)
{
    int lane = threadIdx.x & 63;
    int gwave = (blockIdx.x * blockDim.x + threadIdx.x) >> 6;
    int n = __builtin_amdgcn_readfirstlane(gwave);
    if (n >= N_NODES) return;
    const float* nsp = ns + (size_t)n * 64;
    const float* nvp = nv + (size_t)n * 192;
    float as = 0.f, a0 = 0.f, a1 = 0.f, a2 = 0.f;
    #pragma unroll 8
    for (int u = 0; u < 64; ++u) {
        float ws = Ws[u * 64 + lane];
        float wv = Wv[u * 64 + lane];
        as += nsp[u] * ws;
        a0 += nvp[u * 3 + 0] * wv;
        a1 += nvp[u * 3 + 1] * wv;
        a2 += nvp[u * 3 + 2] * wv;
    }
    s_out[(size_t)n * 64 + lane] = as * LIN_NORM;
    v_out[0 * (size_t)N_NODES * 64 + (size_t)n * 64 + lane] = a0 * LIN_NORM;
    v_out[1 * (size_t)N_NODES * 64 + (size_t)n * 64 + lane] = a1 * LIN_NORM;
    v_out[2 * (size_t)N_NODES * 64 + (size_t)n * 64 + lane] = a2 * LIN_NORM;
}

// ---------------------------------------------------------------------------
// Kernel B: fused edge MLP (MFMA bf16) + tensor product + scatter.
// wave = 64 edges (4 m-tiles of 16); block = 4 waves.
// ---------------------------------------------------------------------------
__global__ __launch_bounds__(256) void k_edge_mfma(
    const float* __restrict__ emb, const float* __restrict__ sh,
    const int* __restrict__ esrc,
    const int* __restrict__ elist, const int* __restrict__ dlist,
    const float* __restrict__ W0,
    const unsigned short* __restrict__ w1f, const unsigned short* __restrict__ w2f,
    const float* __restrict__ s_in, const float* __restrict__ v_in,
    float* __restrict__ s_agg, float* __restrict__ v_agg)
{
    const size_t NP2 = (size_t)N_NODES * 128;
    const size_t NV  = (size_t)N_NODES * 64;

    __shared__ unsigned short h1t[4 * 16 * 72];   // per-wave 16 edges x 72(pad) bf16
    __shared__ float wT[4 * 2 * 16 * 65];         // per-wave 2 groups x 16 edges x 65(pad)

    int lane = threadIdx.x & 63;
    int wid  = threadIdx.x >> 6;
    int q = lane >> 4;
    int c = lane & 15;
    int waveBase = __builtin_amdgcn_readfirstlane(blockIdx.x * 256 + wid * 64);

    unsigned short* myh1 = h1t + wid * (16 * 72);
    float* myT0 = wT + wid * (2 * 16 * 65);
    float* myT1 = myT0 + 16 * 65;

    // W1 B-frags (8 x 16B from pre-swizzled global, L2-hot)
    bf16x8 B1[2][4];
    #pragma unroll
    for (int f = 0; f < 8; ++f)
        B1[f >> 2][f & 3] = *(const bf16x8*)(w1f + (size_t)(f * 64 + lane) * 8);

    // persistent run-merge state
    float accA = 0.f, aB0 = 0.f, aB1 = 0.f, aB2 = 0.f;
    float accD = 0.f, aC0 = 0.f, aC1 = 0.f, aC2 = 0.f;
    int cur1 = dlist[waveBase];
    int cur2 = cur1;

    const float WSCALE = 0.125f * INV_NEIGH;
    const float4* sh4 = (const float4*)sh;
    const float4* emb4 = (const float4*)emb;

    #pragma unroll 1
    for (int mt = 0; mt < 4; ++mt) {
        int ebase = waveBase + mt * 16;
        // per-edge metadata, lane c holds edge c of this tile (vector loads)
        int eidA = elist[ebase + c];
        int srcv = esrc[eidA];
        int dstv = dlist[ebase + c];
        float4 y4 = sh4[eidA];

        // ---- fc0: lane computes h0 for edge c at channels kt*32+q*8+j
        float4 ea = emb4[(size_t)eidA * 2];
        float4 eb = emb4[(size_t)eidA * 2 + 1];
        float emb8[8] = {ea.x, ea.y, ea.z, ea.w, eb.x, eb.y, eb.z, eb.w};
        float h0[16];
        #pragma unroll
        for (int i = 0; i < 16; ++i) h0[i] = 0.f;
        #pragma unroll
        for (int b = 0; b < 8; ++b) {
            #pragma unroll
            for (int kt = 0; kt < 2; ++kt) {
                const float4* wp = (const float4*)(W0 + b * 64 + kt * 32 + q * 8);
                float4 wa = wp[0], wb = wp[1];
                h0[kt * 8 + 0] += emb8[b] * wa.x;
                h0[kt * 8 + 1] += emb8[b] * wa.y;
                h0[kt * 8 + 2] += emb8[b] * wa.z;
                h0[kt * 8 + 3] += emb8[b] * wa.w;
                h0[kt * 8 + 4] += emb8[b] * wb.x;
                h0[kt * 8 + 5] += emb8[b] * wb.y;
                h0[kt * 8 + 6] += emb8[b] * wb.z;
                h0[kt * 8 + 7] += emb8[b] * wb.w;
            }
        }
        bf16x8 A0[2];
        #pragma unroll
        for (int kt = 0; kt < 2; ++kt)
            #pragma unroll
            for (int j = 0; j < 8; ++j)
                A0[kt][j] = (short)f2bf(silu_n(h0[kt * 8 + j] * INV_SQRT8));

        // ---- fc1: 8 MFMA -> D1 (C-layout: col=h1-ch-in-tile, row=edge)
        f32x4 D1[4];
        #pragma unroll
        for (int nt = 0; nt < 4; ++nt) {
            f32x4 z = {0.f, 0.f, 0.f, 0.f};
            D1[nt] = __builtin_amdgcn_mfma_f32_16x16x32_bf16(A0[0], B1[0][nt], z, 0, 0, 0);
            D1[nt] = __builtin_amdgcn_mfma_f32_16x16x32_bf16(A0[1], B1[1][nt], D1[nt], 0, 0, 0);
        }
        // silu + cvt + LDS transpose (C-layout -> [edge][ch] rows, pad 72)
        #pragma unroll
        for (int nt = 0; nt < 4; ++nt)
            #pragma unroll
            for (int r = 0; r < 4; ++r)
                myh1[(q * 4 + r) * 72 + nt * 16 + c] = f2bf(silu_n(D1[nt][r] * 0.125f));
        __builtin_amdgcn_s_waitcnt(0);  // lgkmcnt(0): writes visible to own wave
        bf16x8 A1[2];
        #pragma unroll
        for (int kt = 0; kt < 2; ++kt)
            A1[kt] = *(const bf16x8*)(myh1 + c * 72 + kt * 32 + q * 8);

        // ---- fc2 + TP, in two passes of 2 output groups each
        #pragma unroll 1
        for (int p = 0; p < 2; ++p) {
            // MFMA groups 2p (->myT0) and 2p+1 (->myT1)
            #pragma unroll
            for (int gl = 0; gl < 2; ++gl) {
                int g = 2 * p + gl;
                float* dstT = gl ? myT1 : myT0;
                #pragma unroll
                for (int ntl = 0; ntl < 4; ++ntl) {
                    int f0 = 0 * 16 + g * 4 + ntl;
                    int f1 = 1 * 16 + g * 4 + ntl;
                    bf16x8 b0 = *(const bf16x8*)(w2f + (size_t)(f0 * 64 + lane) * 8);
                    bf16x8 b1 = *(const bf16x8*)(w2f + (size_t)(f1 * 64 + lane) * 8);
                    f32x4 z = {0.f, 0.f, 0.f, 0.f};
                    f32x4 D2 = __builtin_amdgcn_mfma_f32_16x16x32_bf16(A1[0], b0, z, 0, 0, 0);
                    D2 = __builtin_amdgcn_mfma_f32_16x16x32_bf16(A1[1], b1, D2, 0, 0, 0);
                    #pragma unroll
                    for (int r = 0; r < 4; ++r)
                        dstT[(q * 4 + r) * 65 + ntl * 16 + c] = D2[r] * WSCALE;
                }
            }
            __builtin_amdgcn_s_waitcnt(0);  // drain ds_writes before reads

            if (p == 0) {
                // groups A,B : use s_e
                #pragma unroll
                for (int e = 0; e < 16; ++e) {
                    int dst = bcast_i(dstv, e);
                    int src = bcast_i(srcv, e);
                    float y0 = bcast(y4.x, e), yx = bcast(y4.y, e);
                    float yy = bcast(y4.z, e), yz = bcast(y4.w, e);
                    if (dst != cur1) {
                        size_t db = (size_t)cur1 * 128;
                        unsafeAtomicAdd(&s_agg[db + lane], accA);
                        unsafeAtomicAdd(&v_agg[0 * NP2 + db + lane], aB0);
                        unsafeAtomicAdd(&v_agg[1 * NP2 + db + lane], aB1);
                        unsafeAtomicAdd(&v_agg[2 * NP2 + db + lane], aB2);
                        accA = aB0 = aB1 = aB2 = 0.f;
                        cur1 = dst;
                    }
                    float se = s_in[(size_t)src * 64 + lane];
                    float wA = myT0[e * 65 + lane];
                    float wB = myT1[e * 65 + lane];
                    accA = fmaf(wA, se * y0, accA);
                    float bB = wB * se;
                    aB0 = fmaf(bB, yx, aB0);
                    aB1 = fmaf(bB, yy, aB1);
                    aB2 = fmaf(bB, yz, aB2);
                }
            } else {
                // groups C,D : use v_e
                #pragma unroll
                for (int e = 0; e < 16; ++e) {
                    int dst = bcast_i(dstv, e);
                    int src = bcast_i(srcv, e);
                    float y0 = bcast(y4.x, e), yx = bcast(y4.y, e);
                    float yy = bcast(y4.z, e), yz = bcast(y4.w, e);
                    if (dst != cur2) {
                        size_t db = (size_t)cur2 * 128;
                        unsafeAtomicAdd(&s_agg[db + 64 + lane], accD);
                        unsafeAtomicAdd(&v_agg[0 * NP2 + db + 64 + lane], aC0);
                        unsafeAtomicAdd(&v_agg[1 * NP2 + db + 64 + lane], aC1);
                        unsafeAtomicAdd(&v_agg[2 * NP2 + db + 64 + lane], aC2);
                        accD = aC0 = aC1 = aC2 = 0.f;
                        cur2 = dst;
                    }
                    float v0 = v_in[0 * NV + (size_t)src * 64 + lane];
                    float v1 = v_in[1 * NV + (size_t)src * 64 + lane];
                    float v2 = v_in[2 * NV + (size_t)src * 64 + lane];
                    float wC = myT0[e * 65 + lane];
                    float wD = myT1[e * 65 + lane];
                    float dot = v0 * yx + v1 * yy + v2 * yz;
                    accD = fmaf(wD, dot * INV_SQRT3, accD);
                    float bC = wC * y0;
                    aC0 = fmaf(bC, v0, aC0);
                    aC1 = fmaf(bC, v1, aC1);
                    aC2 = fmaf(bC, v2, aC2);
                }
            }
        }
    }
    // final flushes
    {
        size_t db = (size_t)cur1 * 128;
        unsafeAtomicAdd(&s_agg[db + lane], accA);
        unsafeAtomicAdd(&v_agg[0 * NP2 + db + lane], aB0);
        unsafeAtomicAdd(&v_agg[1 * NP2 + db + lane], aB1);
        unsafeAtomicAdd(&v_agg[2 * NP2 + db + lane], aB2);
    }
    {
        size_t db = (size_t)cur2 * 128;
        unsafeAtomicAdd(&s_agg[db + 64 + lane], accD);
        unsafeAtomicAdd(&v_agg[0 * NP2 + db + 64 + lane], aC0);
        unsafeAtomicAdd(&v_agg[1 * NP2 + db + 64 + lane], aC1);
        unsafeAtomicAdd(&v_agg[2 * NP2 + db + 64 + lane], aC2);
    }
}

// ---------------------------------------------------------------------------
// Kernel C: per-node epilogue (R4 version: lane-parallel preload + readlane)
// ---------------------------------------------------------------------------
#define NB 4
__global__ __launch_bounds__(256) void k_node_out(
    const float* __restrict__ ns, const float* __restrict__ nv,
    const float* __restrict__ na,
    const float* __restrict__ Wl2s, const float* __restrict__ Wl2v,
    const float* __restrict__ Wscs, const float* __restrict__ Wscv,
    const float* __restrict__ s_agg, const float* __restrict__ v_agg,
    float* __restrict__ out)
{
    const size_t NP2 = (size_t)N_NODES * 128;
    int lane = threadIdx.x & 63;
    int gwave = (blockIdx.x * blockDim.x + threadIdx.x) >> 6;
    int n0 = __builtin_amdgcn_readfirstlane(gwave * NB);
    if (n0 >= N_NODES) return;

    float aL[NB], aH[NB], bL[3][NB], bH[3][NB], su_r[NB], vu_r[3][NB];
    float pa[NB][4];
    #pragma unroll
    for (int j = 0; j < NB; ++j) {
        size_t nj = (size_t)(n0 + j);
        aL[j] = s_agg[nj * 128 + lane];
        aH[j] = s_agg[nj * 128 + 64 + lane];
        #pragma unroll
        for (int p = 0; p < 3; ++p) {
            bL[p][j] = v_agg[p * NP2 + nj * 128 + lane];
            bH[p][j] = v_agg[p * NP2 + nj * 128 + 64 + lane];
            vu_r[p][j] = nv[nj * 192 + lane * 3 + p];
        }
        su_r[j] = ns[nj * 64 + lane];
        #pragma unroll
        for (int qq = 0; qq < 4; ++qq)
            pa[j][qq] = na[nj * 4 + qq] * SC_NORM;
    }

    float sA[NB], sB[NB], vh[NB][3];
    #pragma unroll
    for (int j = 0; j < NB; ++j) {
        sA[j] = 0.f; sB[j] = 0.f;
        vh[j][0] = 0.f; vh[j][1] = 0.f; vh[j][2] = 0.f;
    }

    for (int u0 = 0; u0 < 64; u0 += 8) {
        #pragma unroll
        for (int i = 0; i < 8; ++i) {
            int u = u0 + i;
            float w1 = Wl2s[u * 128 + lane];
            float w2 = Wl2s[u * 128 + 64 + lane];
            float wv = Wl2v[u * 64 + lane];
            #pragma unroll
            for (int j = 0; j < NB; ++j) {
                float av = bcast(aL[j], u);
                sA[j] += av * w1; sB[j] += av * w2;
                vh[j][0] += bcast(bL[0][j], u) * wv;
                vh[j][1] += bcast(bL[1][j], u) * wv;
                vh[j][2] += bcast(bL[2][j], u) * wv;
            }
        }
    }
    for (int u0 = 0; u0 < 64; u0 += 8) {
        #pragma unroll
        for (int i = 0; i < 8; ++i) {
            int u = u0 + i;
            float w1 = Wl2s[(64 + u) * 128 + lane];
            float w2 = Wl2s[(64 + u) * 128 + 64 + lane];
            float wv = Wl2v[(64 + u) * 64 + lane];
            #pragma unroll
            for (int j = 0; j < NB; ++j) {
                float av = bcast(aH[j], u);
                sA[j] += av * w1; sB[j] += av * w2;
                vh[j][0] += bcast(bH[0][j], u) * wv;
                vh[j][1] += bcast(bH[1][j], u) * wv;
                vh[j][2] += bcast(bH[2][j], u) * wv;
            }
        }
    }
    #pragma unroll
    for (int j = 0; j < NB; ++j) {
        sA[j] *= LIN2_NORM; sB[j] *= LIN2_NORM;
        vh[j][0] *= LIN2_NORM; vh[j][1] *= LIN2_NORM; vh[j][2] *= LIN2_NORM;
    }

    for (int u0 = 0; u0 < 64; u0 += 4) {
        #pragma unroll
        for (int i = 0; i < 4; ++i) {
            int u = u0 + i;
            float suv[NB], vuv[3][NB];
            #pragma unroll
            for (int j = 0; j < NB; ++j) {
                suv[j] = bcast(su_r[j], u);
                vuv[0][j] = bcast(vu_r[0][j], u);
                vuv[1][j] = bcast(vu_r[1][j], u);
                vuv[2][j] = bcast(vu_r[2][j], u);
            }
            #pragma unroll
            for (int qq = 0; qq < 4; ++qq) {
                int idx = u * 4 + qq;
                float wss1 = Wscs[idx * 128 + lane];
                float wss2 = Wscs[idx * 128 + 64 + lane];
                float wsv  = Wscv[idx * 64 + lane];
                #pragma unroll
                for (int j = 0; j < NB; ++j) {
                    float t = suv[j] * pa[j][qq];
                    sA[j] += t * wss1;
                    sB[j] += t * wss2;
                    float tq = pa[j][qq] * wsv;
                    vh[j][0] += vuv[0][j] * tq;
                    vh[j][1] += vuv[1][j] * tq;
                    vh[j][2] += vuv[2][j] * tq;
                }
            }
        }
    }

    #pragma unroll
    for (int j = 0; j < NB; ++j) {
        int n = n0 + j;
        float os = silu_n(sA[j]);
        float g  = silu_n(sB[j]);
        out[(size_t)n * 256 + lane] = os;
        out[(size_t)n * 256 + 64 + lane * 3 + 0] = g * vh[j][0];
        out[(size_t)n * 256 + 64 + lane * 3 + 1] = g * vh[j][1];
        out[(size_t)n * 256 + 64 + lane * 3 + 2] = g * vh[j][2];
    }
}

// ---------------------------------------------------------------------------
extern "C" void kernel_launch(void* const* d_in, const int* in_sizes, int n_in,
                              void* d_out, int out_size, void* d_ws, size_t ws_size,
                              hipStream_t stream)
{
    const float* node_scalars = (const float*)d_in[0];
    const float* node_vectors = (const float*)d_in[1];
    const float* node_attr    = (const float*)d_in[2];
    const float* edge_sh      = (const float*)d_in[3];
    const float* edge_emb     = (const float*)d_in[4];
    const int*   edge_src     = (const int*)d_in[5];
    const int*   edge_dst     = (const int*)d_in[6];
    const float* W_lin1_s = (const float*)d_in[7];
    const float* W_lin1_v = (const float*)d_in[8];
    const float* W_fc0    = (const float*)d_in[9];
    const float* W_fc1    = (const float*)d_in[10];
    const float* W_fc2    = (const float*)d_in[11];
    const float* W_lin2_s = (const float*)d_in[12];
    const float* W_lin2_v = (const float*)d_in[13];
    const float* W_sc_s   = (const float*)d_in[14];
    const float* W_sc_v   = (const float*)d_in[15];
    float* out = (float*)d_out;

    // workspace layout
    float* ws    = (float*)d_ws;
    float* s_agg = ws;                                    // N*128
    float* v_agg = s_agg + (size_t)N_NODES * 128;         // 3*N*128
    float* s_buf = v_agg + 3 * (size_t)N_NODES * 128;     // N*64
    float* v_buf = s_buf + (size_t)N_NODES * 64;          // 3*N*64
    int*   counts = (int*)(v_buf + 3 * (size_t)N_NODES * 64);   // N
    int*   cursor = counts + N_NODES;                     // N
    int*   elist  = cursor + N_NODES;                     // E
    int*   dlist  = elist + N_EDGES;                      // E
    unsigned short* w1f = (unsigned short*)(dlist + N_EDGES);   // 4096
    unsigned short* w2f = w1f + 4096;                     // 16384

    hipMemsetAsync(counts, 0, (size_t)N_NODES * sizeof(int), stream);
    hipMemsetAsync(s_agg, 0, (size_t)N_NODES * 512 * sizeof(float), stream);

    // CSR build (dst-sorted permutation)
    {
        int blocks = (N_EDGES + 255) / 256;
        k_hist<<<blocks, 256, 0, stream>>>(edge_dst, counts);
        k_scan<<<1, SCAN_T, 0, stream>>>(counts, cursor);
        k_fill<<<blocks, 256, 0, stream>>>(edge_dst, cursor, elist, dlist);
    }
    // weight swizzle (bf16 fragment order)
    k_wprep<<<10, 256, 0, stream>>>(W_fc1, W_fc2, w1f, w2f);
    // A: node lin1
    {
        int blocks = (N_NODES + 3) / 4;
        k_node_lin1<<<blocks, 256, 0, stream>>>(node_scalars, node_vectors,
                                                W_lin1_s, W_lin1_v, s_buf, v_buf);
    }
    // B: fused MFMA edge kernel (256 edges/block)
    {
        int blocks = N_EDGES / 256;   // 1250
        k_edge_mfma<<<blocks, 256, 0, stream>>>(edge_emb, edge_sh, edge_src,
                                                elist, dlist, W_fc0, w1f, w2f,
                                                s_buf, v_buf, s_agg, v_agg);
    }
    // C: node epilogue
    {
        int blocks = (N_NODES / NB + 3) / 4;    // 1250
        k_node_out<<<blocks, 256, 0, stream>>>(node_scalars, node_vectors, node_attr,
                                               W_lin2_s, W_lin2_v, W_sc_s, W_sc_v,
                                               s_agg, v_agg, out);
    }
}